// Round 11
// baseline (123.471 us; speedup 1.0000x reference)
//
#include <hip/hip_runtime.h>
#include <hip/hip_bf16.h>
#include <math.h>

#define BATCH 8
#define NPTS 4096
#define CH 128
#define CHUNK 32                      // columns staged per pipeline step
#define NTRI 528                      // 32*33/2 lower-triangle 128x128 tiles

// exp(s/TEMP) = 2^(s * 10 * log2(e)). sqrt(10/ln2) is folded into the
// normalize scale so the GEMM accumulator is already the exp2 argument.
#define SQRT_TEMP_LOG2E 3.79828256f   // sqrt(14.4269504089)

typedef __attribute__((ext_vector_type(4))) float    f32x4;
typedef __attribute__((ext_vector_type(4))) int      i32x4;
typedef __attribute__((ext_vector_type(8))) short    bf16x8;
typedef __attribute__((ext_vector_type(4))) _Float16 f16x4;

typedef __attribute__((address_space(3))) unsigned int lds_uint;
typedef __attribute__((address_space(1))) const unsigned int gbl_uint;

__device__ __forceinline__ void load_lds16(const void* g, const void* l) {
    __builtin_amdgcn_global_load_lds((gbl_uint*)g, (lds_uint*)l, 16, 0, 0);
}

__device__ __forceinline__ float fast_exp2(float x) {
    return __builtin_amdgcn_exp2f(x);
}

// 16x16x16 f16 MFMA. Verified convention (from the working class-GEMM):
//   mfma16(X, Y, C): OUT(lane15 = Y.lane15-index, elemslot quad*4+r =
//   X.lane15-index) = sum_e X[X.lane15][e] * Y[Y.lane15][e]
// where e is the element index (quad*4+j) of both operands.
__device__ __forceinline__ f32x4 mfma16(f16x4 a, f16x4 b, f32x4 c) {
#if __has_builtin(__builtin_amdgcn_mfma_f32_16x16x16f16)
    return __builtin_amdgcn_mfma_f32_16x16x16f16(a, b, c, 0, 0, 0);
#else
    f32x4 d = c;
    asm volatile("v_mfma_f32_16x16x16_f16 %0, %1, %2, %0"
                 : "+v"(d) : "v"(a), "v"(b));
    return d;
#endif
}

// ---------------------------------------------------------------------------
// Kernel 1: coalesced two-pass L2-normalize (R9, verified).
// ---------------------------------------------------------------------------
__global__ __launch_bounds__(256) void normalize_kernel(
    const float* __restrict__ f, __hip_bfloat16* __restrict__ vn,
    float* __restrict__ pos, float* __restrict__ neg, float* __restrict__ out)
{
    const int blk = blockIdx.x;            // 512 blocks
    const int b = blk >> 6;                // 64 blocks per batch
    const int n0 = (blk & 63) * 64;        // 64 points per block
    const int nl = threadIdx.x & 63;       // point lane
    const int cg = threadIdx.x >> 6;       // channel quarter (32 ch)
    const float* base = f + (size_t)b * CH * NPTS + (size_t)(cg * 32) * NPTS
                          + n0 + nl;

    __shared__ float red[4][64];
    __shared__ float scl[64];
    __shared__ short ostage[64 * CH];      // 16 KB staging tile

    float ss = 0.0f;
    #pragma unroll
    for (int c = 0; c < 32; c++) {
        float v = base[(size_t)c * NPTS];
        ss += v * v;
    }
    red[cg][nl] = ss;
    __syncthreads();
    if (cg == 0) {
        float s = red[0][nl] + red[1][nl] + red[2][nl] + red[3][nl];
        scl[nl] = SQRT_TEMP_LOG2E / fmaxf(sqrtf(s), 1e-12f);
    }
    __syncthreads();
    const float scale = scl[nl];

    #pragma unroll
    for (int k = 0; k < 4; k++) {
        union { __hip_bfloat16 h[8]; uint4 u; } pk;
        #pragma unroll
        for (int j = 0; j < 8; j++) {
            float v = base[(size_t)(k * 8 + j) * NPTS] * scale;
            pk.h[j] = __float2bfloat16(v);
        }
        const int ch8 = cg * 4 + k;
        const int phys = (nl << 4) | (ch8 ^ (nl & 15));
        *(uint4*)&ostage[phys * 8] = pk.u;
    }
    __syncthreads();

    __hip_bfloat16* ob = vn + ((size_t)b * NPTS + n0) * CH;
    const int t = threadIdx.x;
    #pragma unroll
    for (int it = 0; it < 4; it++) {
        const int L = it * 256 + t;
        const int pt = L >> 4, c8 = L & 15;
        const int phys = (pt << 4) | (c8 ^ (pt & 15));
        *(uint4*)(ob + (size_t)L * 8) = *(const uint4*)&ostage[phys * 8];
    }

    if (cg == 0) pos[b * NPTS + n0 + nl] = 0.0f;
    else if (cg == 1) neg[b * NPTS + n0 + nl] = 0.0f;
    if (blk == 0 && t == 0) out[0] = 0.0f;
}

// ---------------------------------------------------------------------------
// Kernel 2: SYMMETRIC lower-triangle tile GEMM. exp(S/T) is symmetric, so
// only tiles with ct <= rt are computed (528 of 1024 per batch = 51.6% of
// the MFMA+exp work). Off-diagonal tiles feed BOTH row sums (as before) and
// col sums via an in-register fragment transpose done BY THE MATRIX PIPE:
//   tr  = mfma16(eh, idf, 0)   // idf[y][e]=[y==e]  => tr(lane15=col,
//                              //   elem=row) = e[row][col]  (exact: f16
//                              //   values pass through f32 untouched)
//   qc  = mfma16(ohr, trh, qc) // ohr[class][row]=[labR(row)==class]
//                              // => qc(lane15=col, elem=class)
// Col class-sums accumulate in LDS (colp/colt[128], LDS atomics), flushed
// once per block; row sums accumulate in registers as before. Diagonal
// tiles run the old path (ddiag) and skip the col path.
//
// Pipeline: 4 bodies, proven counted-vmcnt ring (NBUF=3, stage distance 2,
// EXACTLY 2 vm ops per body incl. a dead stage at body 2; body 3 stages
// nothing and has no trailing wait). Prologue vm order: labC(1)+labR(1)+
// afrag(8)+stage0(2)+stage1(2)=14; vmcnt(2) retires all but stage1 => labels
// + chunk 0 resident. Label pads are loaded redundantly by all 4 waves
// (identical bytes, keeps per-wave vm counts uniform); lr/lrq hoisted from
// LDS right after that vmcnt (own wave's copy retired).
//
// Tripwires: WRITE_SIZE (spill; est ~110 unified regs < 128 cap — R7 lesson:
// AGPRs count), absmax (transpose-convention bug), SQ_LDS_BANK_CONFLICT.
// ---------------------------------------------------------------------------
__global__ __launch_bounds__(256, 4) void tile_kernel(
    const __hip_bfloat16* __restrict__ vn, const int* __restrict__ labels,
    float* __restrict__ pos, float* __restrict__ neg)
{
    __shared__ short lB[3][CHUNK * CH];    // 24 KB ring
    __shared__ int labPadC[256];           // col labels (written 2x, benign)
    __shared__ int labPadR[256];           // row labels
    __shared__ float colp[128], colt[128];

    const int t = blockIdx.x, b = blockIdx.y;
    int rt = (int)((sqrtf((float)(8 * t + 1)) - 1.0f) * 0.5f);
    while (rt * (rt + 1) / 2 > t) rt--;
    while ((rt + 1) * (rt + 2) / 2 <= t) rt++;
    const int ct = t - rt * (rt + 1) / 2;
    const bool isdiag = (rt == ct);

    const int tid = threadIdx.x;
    const int w = tid >> 6, lane = tid & 63;
    const int lane15 = lane & 15, quad = lane >> 4;
    const int row0 = rt * 128, col0 = ct * 128;
    const __hip_bfloat16* vb = vn + (size_t)b * NPTS * CH;
    const int* labb = labels + b * NPTS;

    // Stage one 32-col chunk -> ring buffer (proven XOR-source swizzle,
    // 0 bank conflicts). 4 waves x 2 iters x 4 rows.
    auto stage = [&](int buf, int chunk) {
        const __hip_bfloat16* Bb = vb + (size_t)(col0 + chunk * CHUNK) * CH;
        #pragma unroll
        for (int i = 0; i < 2; i++) {
            int ldsrow = w * 8 + i * 4;             // wave-uniform
            int r = ldsrow + quad;                  // row this lane feeds
            int g = lane15 ^ (r & 15);              // swizzled global chunk
            load_lds16(Bb + (size_t)r * CH + g * 8, &lB[buf][ldsrow * CH]);
        }
    };

    // ---- prologue (vm order matters; see header comment).
    load_lds16(labb + col0 + (lane & 31) * 4, labPadC);  // all waves dup
    load_lds16(labb + row0 + (lane & 31) * 4, labPadR);

    bf16x8 afrag[2][4];
    #pragma unroll
    for (int mi = 0; mi < 2; mi++) {
        const int row_l = w * 32 + mi * 16 + lane15;
        const __hip_bfloat16* Arow = vb + (size_t)(row0 + row_l) * CH;
        #pragma unroll
        for (int ks = 0; ks < 4; ks++)
            afrag[mi][ks] = *(const bf16x8*)(Arow + (ks * 4 + quad) * 8);
    }

    stage(0, 0);
    stage(1, 1);

    if (tid < 128) { colp[tid] = 0.0f; colt[tid] = 0.0f; }

    int vad[2][4];
    #pragma unroll
    for (int ni = 0; ni < 2; ni++)
        #pragma unroll
        for (int ks = 0; ks < 4; ks++)
            vad[ni][ks] = (((ni * 16 + lane15) * CH) +
                           (((ks * 4 + quad) ^ lane15) << 3)) * 2;

    f16x4 idf;                              // identity fragment (transpose)
    #pragma unroll
    for (int j = 0; j < 4; j++)
        idf[j] = (quad * 4 + j == lane15) ? (_Float16)1.0f : (_Float16)0.0f;

    f32x4 qout[2] = {{0.0f, 0.0f, 0.0f, 0.0f}, {0.0f, 0.0f, 0.0f, 0.0f}};
    float ddiag[2] = {0.0f, 0.0f};
    const f32x4 zf = {0.0f, 0.0f, 0.0f, 0.0f};
    f32x4 accA[2][2], accB[2][2];

#define MFMA_PH(BUF_, ACC_)                                                   \
    {                                                                         \
        _Pragma("unroll")                                                     \
        for (int ni = 0; ni < 2; ni++) {                                      \
            bf16x8 bf = *(const bf16x8*)((const char*)(&lB[0][0]) +           \
                         (BUF_) * (CHUNK * CH * 2) + vad[ni][0]);             \
            ACC_[0][ni] = __builtin_amdgcn_mfma_f32_16x16x32_bf16(            \
                bf, afrag[0][0], zf, 0, 0, 0);                                \
            ACC_[1][ni] = __builtin_amdgcn_mfma_f32_16x16x32_bf16(            \
                bf, afrag[1][0], zf, 0, 0, 0);                                \
        }                                                                     \
        _Pragma("unroll")                                                     \
        for (int ks = 1; ks < 4; ks++) {                                      \
            _Pragma("unroll")                                                 \
            for (int ni = 0; ni < 2; ni++) {                                  \
                bf16x8 bf = *(const bf16x8*)((const char*)(&lB[0][0]) +       \
                             (BUF_) * (CHUNK * CH * 2) + vad[ni][ks]);        \
                ACC_[0][ni] = __builtin_amdgcn_mfma_f32_16x16x32_bf16(        \
                    bf, afrag[0][ks], ACC_[0][ni], 0, 0, 0);                  \
                ACC_[1][ni] = __builtin_amdgcn_mfma_f32_16x16x32_bf16(        \
                    bf, afrag[1][ks], ACC_[1][ni], 0, 0, 0);                  \
            }                                                                 \
        }                                                                     \
    }

#define EPI_PH(EC_, ACC_)                                                     \
    {                                                                         \
        _Pragma("unroll")                                                     \
        for (int ni = 0; ni < 2; ni++) {                                      \
            const i32x4 lc = *(const i32x4*)&labPadC[(EC_) * CHUNK + ni * 16  \
                                                     + quad * 4];             \
            f16x4 oh;                                                         \
            _Pragma("unroll")                                                 \
            for (int j = 0; j < 4; j++)                                       \
                oh[j] = (lc[j] == lane15) ? (_Float16)1.0f : (_Float16)0.0f;  \
            const int colblk = col0 + (EC_) * CHUNK + ni * 16;                \
            f32x4 qc = zf;                                                    \
            _Pragma("unroll")                                                 \
            for (int mi = 0; mi < 2; mi++) {                                  \
                f16x4 eh;                                                     \
                _Pragma("unroll")                                             \
                for (int r = 0; r < 4; r++)                                   \
                    eh[r] = (_Float16)fast_exp2(ACC_[mi][ni][r]);             \
                if (colblk == row0 + w * 32 + mi * 16) {  /* wave-uniform */  \
                    _Pragma("unroll")                                         \
                    for (int r = 0; r < 4; r++)                               \
                        if (lane15 == quad * 4 + r)                           \
                            ddiag[mi] += (float)eh[r];                        \
                }                                                             \
                qout[mi] = mfma16(oh, eh, qout[mi]);                          \
                if (!isdiag) {                                                \
                    f32x4 tr = mfma16(eh, idf, zf);   /* e^T fragment */      \
                    f16x4 trh, ohr;                                           \
                    _Pragma("unroll")                                         \
                    for (int r = 0; r < 4; r++)                               \
                        trh[r] = (_Float16)tr[r];     /* exact */             \
                    _Pragma("unroll")                                         \
                    for (int j = 0; j < 4; j++)                               \
                        ohr[j] = (lrq[mi][j] == lane15) ? (_Float16)1.0f      \
                                                        : (_Float16)0.0f;     \
                    qc = mfma16(ohr, trh, qc);                                \
                }                                                             \
            }                                                                 \
            if (!isdiag) {                                                    \
                float tc = qc[0] + qc[1] + qc[2] + qc[3];                     \
                const int cl = labPadC[(EC_) * CHUNK + ni * 16 + lane15];     \
                float pc = ((cl >> 2) == quad) ? qc[cl & 3] : 0.0f;           \
                pc += __shfl_xor(pc, 16);  pc += __shfl_xor(pc, 32);          \
                tc += __shfl_xor(tc, 16);  tc += __shfl_xor(tc, 32);          \
                if (lane < 16) {                                              \
                    atomicAdd(&colp[(EC_) * CHUNK + ni * 16 + lane15], pc);   \
                    atomicAdd(&colt[(EC_) * CHUNK + ni * 16 + lane15], tc);   \
                }                                                             \
            }                                                                 \
        }                                                                     \
    }

    asm volatile("s_waitcnt vmcnt(2)" ::: "memory");   // labels+chunk0 ready
    int lr[2];
    i32x4 lrq[2];
    #pragma unroll
    for (int mi = 0; mi < 2; mi++) {
        lr[mi]  = labPadR[w * 32 + mi * 16 + lane15];
        lrq[mi] = *(const i32x4*)&labPadR[w * 32 + mi * 16 + quad * 4];
    }

    // body 0: chunk 0 (buf 0), stage chunk 2 -> buf 2
    __builtin_amdgcn_s_barrier();
    __builtin_amdgcn_s_setprio(1);
    MFMA_PH(0, accA);
    __builtin_amdgcn_s_setprio(0);
    stage(2, 2);
    asm volatile("s_waitcnt vmcnt(2)" ::: "memory");
    // body 1: chunk 1 (buf 1), stage chunk 3 -> buf 0, EPI chunk 0
    __builtin_amdgcn_s_barrier();
    __builtin_amdgcn_s_setprio(1);
    MFMA_PH(1, accB);
    __builtin_amdgcn_s_setprio(0);
    stage(0, 3);
    EPI_PH(0, accA);
    asm volatile("s_waitcnt vmcnt(2)" ::: "memory");
    // body 2: chunk 2 (buf 2), dead stage -> buf 1 (keeps vmcnt count), EPI 1
    __builtin_amdgcn_s_barrier();
    __builtin_amdgcn_s_setprio(1);
    MFMA_PH(2, accA);
    __builtin_amdgcn_s_setprio(0);
    stage(1, 0);                           // dead (re-stage chunk 0 data)
    EPI_PH(1, accB);
    asm volatile("s_waitcnt vmcnt(2)" ::: "memory");
    // body 3: chunk 3 (buf 0), no stage / no trailing wait, EPI 2 then 3
    __builtin_amdgcn_s_barrier();
    __builtin_amdgcn_s_setprio(1);
    MFMA_PH(0, accB);
    __builtin_amdgcn_s_setprio(0);
    EPI_PH(2, accA);
    EPI_PH(3, accB);

#undef EPI_PH
#undef MFMA_PH

    // ---- row flush. qout[mi] elem (lane,r) = q[class=quad*4+r, row=lane15].
    #pragma unroll
    for (int mi = 0; mi < 2; mi++) {
        float p = -ddiag[mi], tt = -ddiag[mi];
        #pragma unroll
        for (int r = 0; r < 4; r++) {
            float v = qout[mi][r];
            tt += v;
            p  += (quad * 4 + r == lr[mi]) ? v : 0.0f;
        }
        p  += __shfl_xor(p, 16);   p  += __shfl_xor(p, 32);
        tt += __shfl_xor(tt, 16);  tt += __shfl_xor(tt, 32);
        if (lane < 16) {
            const int row_l = w * 32 + mi * 16 + lane15;
            atomicAdd(&pos[b * NPTS + row0 + row_l], p);
            atomicAdd(&neg[b * NPTS + row0 + row_l], tt - p);
        }
    }

    // ---- col flush (off-diagonal tiles only).
    __syncthreads();
    if (!isdiag && tid < 128) {
        float p = colp[tid], tt = colt[tid];
        atomicAdd(&pos[b * NPTS + col0 + tid], p);
        atomicAdd(&neg[b * NPTS + col0 + tid], tt - p);
    }
}

// ---------------------------------------------------------------------------
// Kernel 3: mean of log((p+n)/p) over 32768 rows. 32 blocks x 256 threads;
// out zeroed by normalize_kernel, stream order makes the atomic safe.
// ---------------------------------------------------------------------------
__global__ __launch_bounds__(256) void finalize_kernel(
    const float* __restrict__ pos, const float* __restrict__ neg,
    float* __restrict__ out)
{
    int base = blockIdx.x * 1024 + threadIdx.x;
    float acc = 0.0f;
    #pragma unroll
    for (int k = 0; k < 4; k++) {
        int i = base + k * 256;
        float p = pos[i];
        float t = p + neg[i];
        acc += __logf(t / p);   // == -log(p / (p+n))
    }
    #pragma unroll
    for (int off = 32; off; off >>= 1) acc += __shfl_down(acc, off);
    __shared__ float red[4];
    if ((threadIdx.x & 63) == 0) red[threadIdx.x >> 6] = acc;
    __syncthreads();
    if (threadIdx.x == 0) {
        float v = red[0] + red[1] + red[2] + red[3];
        atomicAdd(out, v * (1.0f / (BATCH * NPTS)));
    }
}

extern "C" void kernel_launch(void* const* d_in, const int* in_sizes, int n_in,
                              void* d_out, int out_size, void* d_ws, size_t ws_size,
                              hipStream_t stream)
{
    const float* features = (const float*)d_in[0];
    const int*   labels   = (const int*)d_in[1];
    float*       out      = (float*)d_out;

    // Workspace: vn bf16 [8][4096][128] = 8 MB, then pos/neg fp32.
    __hip_bfloat16* vn = (__hip_bfloat16*)d_ws;
    float* pos = (float*)((char*)d_ws + (size_t)BATCH * NPTS * CH * sizeof(__hip_bfloat16));
    float* neg = pos + BATCH * NPTS;

    // 512 blocks x 64 points, coalesced two-pass normalize (R9, verified).
    hipLaunchKernelGGL(normalize_kernel, dim3(512), dim3(256), 0, stream,
                       features, vn, pos, neg, out);
    // Lower-triangle 128x128 tiles: 528 per batch x 8 batches = 4224 blocks.
    hipLaunchKernelGGL(tile_kernel, dim3(NTRI, BATCH), dim3(256), 0, stream,
                       vn, labels, pos, neg);
    hipLaunchKernelGGL(finalize_kernel, dim3(32), dim3(256), 0, stream, pos, neg, out);
}